// Round 6
// baseline (265.571 us; speedup 1.0000x reference)
//
#include <hip/hip_runtime.h>
#include <hip/hip_bf16.h>
#include <hip/hip_fp16.h>
#include <math.h>

#define D 128
#define BIN_SHIFT 8      // 256 rows per coarse bin
#define BIN_ROWS 256
#define NB_MAX 512       // >= nbins (391 for 100k nodes)
#define CPAD 16          // ints; one 64B line per coarse cursor
#define AW 4096          // edges per stage-A block window

typedef _Float16 half8 __attribute__((ext_vector_type(8)));
typedef float floatx4 __attribute__((ext_vector_type(4)));
typedef float floatx2 __attribute__((ext_vector_type(2)));

// ---------------- W transpose + fp16 convert: wt[n][k] = f16(W[k][n]) ------
// Blocks 0-1 also zero the 512 coarse-bin counters (no memset dispatch).
__global__ void gcn_wt_kernel(const float* __restrict__ W,
                              unsigned short* __restrict__ wt,
                              int* __restrict__ cbin) {
    const int i = blockIdx.x * 256 + threadIdx.x;  // i = n*128 + k
    const int n = i >> 7, k = i & 127;
    wt[i] = __half_as_ushort(__float2half_rn(W[k * D + n]));
    if (blockIdx.x < 2) cbin[blockIdx.x * 256 + threadIdx.x] = 0;  // NB_MAX=512
}

// ---------------- GEMM: support_f16 = fp16(x @ W), f16 MFMA ----------------
__global__ __launch_bounds__(256) void gcn_gemm_kernel(
        const float* __restrict__ x, const unsigned short* __restrict__ wt,
        unsigned short* __restrict__ support2, int n_nodes) {
    const int wave = threadIdx.x >> 6;
    const int lane = threadIdx.x & 63;
    const int q = lane >> 4;      // 0..3
    const int n16 = lane & 15;    // 0..15
    const int row_base = blockIdx.x * 128 + wave * 32;  // 32 rows per wave
    if (row_base >= n_nodes) return;   // 32 | 100000, no partial waves

    const half8* wt8 = (const half8*)wt;  // 16 B = 8 halves; wt row = 16 half8

    floatx4 acc[2][8];
#pragma unroll
    for (int mt = 0; mt < 2; ++mt)
#pragma unroll
        for (int nt = 0; nt < 8; ++nt) acc[mt][nt] = (floatx4){0.f, 0.f, 0.f, 0.f};

#pragma unroll
    for (int kc = 0; kc < 4; ++kc) {
        half8 b[8];
#pragma unroll
        for (int nt = 0; nt < 8; ++nt)
            b[nt] = wt8[(nt * 16 + n16) * 16 + kc * 4 + q];
#pragma unroll
        for (int mt = 0; mt < 2; ++mt) {
            const float* xp = x + (size_t)(row_base + mt * 16 + n16) * D
                                + kc * 32 + q * 8;
            const float4 f0 = *(const float4*)xp;
            const float4 f1 = *(const float4*)(xp + 4);
            half8 a;
            a[0] = (_Float16)f0.x; a[1] = (_Float16)f0.y;
            a[2] = (_Float16)f0.z; a[3] = (_Float16)f0.w;
            a[4] = (_Float16)f1.x; a[5] = (_Float16)f1.y;
            a[6] = (_Float16)f1.z; a[7] = (_Float16)f1.w;
#pragma unroll
            for (int nt = 0; nt < 8; ++nt)
                acc[mt][nt] = __builtin_amdgcn_mfma_f32_16x16x32_f16(
                    a, b[nt], acc[mt][nt], 0, 0, 0);
        }
    }

#pragma unroll
    for (int mt = 0; mt < 2; ++mt) {
        const int r0 = row_base + mt * 16 + q * 4;
#pragma unroll
        for (int nt = 0; nt < 8; ++nt) {
            const int col = nt * 16 + n16;
#pragma unroll
            for (int i = 0; i < 4; ++i)
                support2[(size_t)(r0 + i) * D + col] =
                    __half_as_ushort(__float2half_rn(acc[mt][nt][i]));
        }
    }
}

// ---------------- coarse-bin histogram (391 bins), LDS-aggregated ----------
__global__ __launch_bounds__(256) void gcn_chist_kernel(
        const int* __restrict__ erow, int* __restrict__ cbin, int n_edges) {
    __shared__ int h[NB_MAX];
    const int t = threadIdx.x;
    h[t] = 0;
    h[t + 256] = 0;
    __syncthreads();
    const int stride = gridDim.x * 256 * 4;
    const int nv = n_edges & ~3;
    for (int i = (blockIdx.x * 256 + t) * 4; i + 3 < n_edges; i += stride) {
        const int4 r = *(const int4*)(erow + i);
        atomicAdd(&h[r.x >> BIN_SHIFT], 1);
        atomicAdd(&h[r.y >> BIN_SHIFT], 1);
        atomicAdd(&h[r.z >> BIN_SHIFT], 1);
        atomicAdd(&h[r.w >> BIN_SHIFT], 1);
    }
    if (blockIdx.x == 0) {  // scalar tail (none for 1.6M, kept for safety)
        for (int i = nv + t; i < n_edges; i += 256)
            atomicAdd(&h[erow[i] >> BIN_SHIFT], 1);
    }
    __syncthreads();
    if (h[t] > 0) atomicAdd(&cbin[t], h[t]);
    if (h[t + 256] > 0) atomicAdd(&cbin[t + 256], h[t + 256]);
}

// ---------------- scan of 391 coarse-bin totals (single block, 512 thr) ----
__global__ __launch_bounds__(512) void gcn_cscan_kernel(
        const int* __restrict__ cbin, int* __restrict__ cbase,
        int* __restrict__ ccur, int* __restrict__ offsets,
        int nbins, int n_nodes, int n_edges) {
    __shared__ int sm[512];
    const int t = threadIdx.x;
    const int v = (t < nbins) ? cbin[t] : 0;
    sm[t] = v;
    __syncthreads();
    for (int off = 1; off < 512; off <<= 1) {
        int tv = (t >= off) ? sm[t - off] : 0;
        __syncthreads();
        sm[t] += tv;
        __syncthreads();
    }
    const int ex = sm[t] - v;
    if (t < nbins) { cbase[t] = ex; ccur[t * CPAD] = ex; }
    if (t == 0) { cbase[nbins] = n_edges; offsets[n_nodes] = n_edges; }
}

// ---------------- Stage A (lite): count -> reserve -> direct scatter -------
// No LDS record staging, no block-wide scans, no ordered write-out: 3
// barriers, 4 KB LDS (was ~22 barriers / 38 KB). Scattered 8 B tmp8 writes
// land in ~10-edge runs per bin range; L2 byte-enable merge absorbs them.
__global__ __launch_bounds__(256) void gcn_binA_kernel(
        const int* __restrict__ erow, const int* __restrict__ ecol,
        const float* __restrict__ eval, int* __restrict__ ccur,
        uint2* __restrict__ tmp8, int n_edges, int nbins) {
    __shared__ int hist[NB_MAX];   // counts, then global cursors
    __shared__ int base[NB_MAX];
    const int t = threadIdx.x;
    const int w0 = blockIdx.x * AW;
    const int wend = min(w0 + AW, n_edges);

    hist[t] = 0;
    hist[t + 256] = 0;
    __syncthreads();

    // pass 1: per-bin counts for this window
    for (int i = w0 + t; i < wend; i += 256)
        atomicAdd(&hist[erow[i] >> BIN_SHIFT], 1);
    __syncthreads();

    // reserve contiguous ranges in each bin (one global atomic per used bin)
#pragma unroll
    for (int s = 0; s < 2; ++s) {
        const int b = t + s * 256;
        const int c = hist[b];
        base[b] = (b < nbins && c > 0) ? atomicAdd(&ccur[b * CPAD], c) : 0;
    }
    __syncthreads();
    hist[t] = base[t];
    hist[t + 256] = base[t + 256];
    __syncthreads();

    // pass 2: direct scattered placement (edge data L2/L1-hot from pass 1)
    for (int i = w0 + t; i < wend; i += 256) {
        const int r = erow[i];
        const int c = ecol[i];
        const unsigned short vh = __half_as_ushort(__float2half_rn(eval[i]));
        const int pos = atomicAdd(&hist[r >> BIN_SHIFT], 1);
        tmp8[pos] = make_uint2(((unsigned)r << 15) | vh, (unsigned)c);
    }
}

// ---------------- Stage B: per-row count + scan + CSR placement ------------
__global__ __launch_bounds__(256) void gcn_binB_kernel(
        const uint2* __restrict__ tmp8, const int* __restrict__ cbase,
        int* __restrict__ offsets,
        unsigned int* __restrict__ rec4, int n_nodes) {
    __shared__ int cnt[BIN_ROWS];
    __shared__ int sm[BIN_ROWS];
    const int bin = blockIdx.x;
    const int r0 = bin << BIN_SHIFT;
    const int t = threadIdx.x;
    cnt[t] = 0;
    __syncthreads();

    const int beg = cbase[bin];
    const int end = cbase[bin + 1];

    // pass 1: per-row histogram within the bin
    for (int i = beg + t; i < end; i += 256)
        atomicAdd(&cnt[(int)(tmp8[i].x >> 15) - r0], 1);
    __syncthreads();

    // exclusive scan over 256 counters (1 per thread)
    const int v = cnt[t];
    sm[t] = v;
    __syncthreads();
    for (int off = 1; off < 256; off <<= 1) {
        int tv = (t >= off) ? sm[t - off] : 0;
        __syncthreads();
        sm[t] += tv;
        __syncthreads();
    }
    const int mypos = beg + sm[t] - v;   // global CSR start for row r0+t

    const int row = r0 + t;
    if (row < n_nodes) offsets[row] = mypos;
    __syncthreads();
    cnt[t] = mypos;                      // per-row cursor
    __syncthreads();

    // pass 2: placement (tmp8 slice L2-hot from pass 1)
    for (int i = beg + t; i < end; i += 256) {
        const uint2 p = tmp8[i];
        const int pos = atomicAdd(&cnt[(int)(p.x >> 15) - r0], 1);
        rec4[pos] = (p.y << 15) | (p.x & 0x7FFFu);
    }
}

// ---------------- per-node reduction + fused tanh --------------------------
// 2 edges per load instruction: lanes 0-31 cover edge 2j, lanes 32-63 edge
// 2j+1, each lane reads 8 B (uint2) of the support row -> half the vmem
// instructions at 512 B/request. Cross-half combine via one shfl_xor(32)
// per accumulator; low half-wave does coalesced float4 stores.
__global__ __launch_bounds__(256) void gcn_gather_kernel(
        const unsigned int* __restrict__ support_u,
        const unsigned int* __restrict__ rec4,
        const int* __restrict__ offsets,
        float* __restrict__ out, int n_nodes) {
    const int node = __builtin_amdgcn_readfirstlane(
        blockIdx.x * 4 + (threadIdx.x >> 6));
    const int lane = threadIdx.x & 63;
    const int half = lane >> 5;     // which edge of the pair
    const int l32 = lane & 31;      // covers cols l32*4 .. l32*4+3
    if (node >= n_nodes) return;

    const uint2* support8 = (const uint2*)support_u;  // row = 32 uint2

    const int beg = offsets[node];
    const int end = offsets[node + 1];

    float a0 = 0.f, a1 = 0.f, a2 = 0.f, a3 = 0.f;   // even-j pairs
    float b0 = 0.f, b1 = 0.f, b2 = 0.f, b3 = 0.f;   // odd-j pairs
    int e = beg;
    // 4 pairs (8 edges) per iteration
    for (; e + 7 < end; e += 8) {
        unsigned r[4];
        uint2 s[4];
#pragma unroll
        for (int j = 0; j < 4; ++j) r[j] = rec4[e + 2 * j + half];
#pragma unroll
        for (int j = 0; j < 4; ++j)
            s[j] = support8[(size_t)(r[j] >> 15) * 32 + l32];
#pragma unroll
        for (int j = 0; j < 4; ++j) {
            const float v = __half2float(__ushort_as_half((unsigned short)(r[j] & 0x7FFFu)));
            const float c0 = __half2float(__ushort_as_half((unsigned short)(s[j].x & 0xFFFFu)));
            const float c1 = __half2float(__ushort_as_half((unsigned short)(s[j].x >> 16)));
            const float c2 = __half2float(__ushort_as_half((unsigned short)(s[j].y & 0xFFFFu)));
            const float c3 = __half2float(__ushort_as_half((unsigned short)(s[j].y >> 16)));
            if (j & 1) { b0 += v * c0; b1 += v * c1; b2 += v * c2; b3 += v * c3; }
            else       { a0 += v * c0; a1 += v * c1; a2 += v * c2; a3 += v * c3; }
        }
    }
    // 1 pair (2 edges) per iteration
    for (; e + 1 < end; e += 2) {
        const unsigned r = rec4[e + half];
        const uint2 s = support8[(size_t)(r >> 15) * 32 + l32];
        const float v = __half2float(__ushort_as_half((unsigned short)(r & 0x7FFFu)));
        a0 += v * __half2float(__ushort_as_half((unsigned short)(s.x & 0xFFFFu)));
        a1 += v * __half2float(__ushort_as_half((unsigned short)(s.x >> 16)));
        a2 += v * __half2float(__ushort_as_half((unsigned short)(s.y & 0xFFFFu)));
        a3 += v * __half2float(__ushort_as_half((unsigned short)(s.y >> 16)));
    }
    // tail single edge: only the low half contributes (high half would dup)
    if (e < end) {
        const unsigned r = rec4[e];
        const uint2 s = support8[(size_t)(r >> 15) * 32 + l32];
        const float v = half ? 0.f
            : __half2float(__ushort_as_half((unsigned short)(r & 0x7FFFu)));
        a0 += v * __half2float(__ushort_as_half((unsigned short)(s.x & 0xFFFFu)));
        a1 += v * __half2float(__ushort_as_half((unsigned short)(s.x >> 16)));
        a2 += v * __half2float(__ushort_as_half((unsigned short)(s.y & 0xFFFFu)));
        a3 += v * __half2float(__ushort_as_half((unsigned short)(s.y >> 16)));
    }

    a0 += b0; a1 += b1; a2 += b2; a3 += b3;
    // combine the two half-wave partials (lane l <-> lane l^32)
    a0 += __shfl_xor(a0, 32);
    a1 += __shfl_xor(a1, 32);
    a2 += __shfl_xor(a2, 32);
    a3 += __shfl_xor(a3, 32);

    if (half == 0) {
        floatx4 res;
        res.x = tanhf(a0); res.y = tanhf(a1);
        res.z = tanhf(a2); res.w = tanhf(a3);
        floatx4* out4 = (floatx4*)out;
        // non-temporal: keep the 50MB out stream from evicting support in L2
        __builtin_nontemporal_store(res, &out4[(size_t)node * 32 + l32]);
    }
}

extern "C" void kernel_launch(void* const* d_in, const int* in_sizes, int n_in,
                              void* d_out, int out_size, void* d_ws, size_t ws_size,
                              hipStream_t stream) {
    const float* x    = (const float*)d_in[0];
    const float* W    = (const float*)d_in[1];
    const int*   erow = (const int*)d_in[2];
    const int*   ecol = (const int*)d_in[3];
    const float* eval = (const float*)d_in[4];
    float* out = (float*)d_out;

    const int n_nodes = in_sizes[0] / D;   // 100000
    const int n_edges = in_sizes[2];       // 1600000
    const int nbins = (n_nodes + BIN_ROWS - 1) >> BIN_SHIFT;      // 391

    // Workspace layout (16B alignment preserved per chunk)
    unsigned short* support2 = (unsigned short*)d_ws;             // 25.6 MB
    unsigned short* wt = support2 + (size_t)n_nodes * D;          // 32 KB
    uint2* tmp8   = (uint2*)(wt + D * D);                         // 12.8 MB
    unsigned int* rec4 = (unsigned int*)(tmp8 + n_edges);         // 6.4 MB
    int*  offsets = (int*)(rec4 + n_edges);                       // n_nodes+1
    int*  cbin    = offsets + n_nodes + 1;                        // NB_MAX
    int*  cbase   = cbin + NB_MAX;                                // NB_MAX+1
    int*  ccur    = cbase + NB_MAX + 1;                           // nbins*CPAD

    // 1) wt = f16(W^T) (+ zero coarse-bin counters); support = fp16(x @ W)
    gcn_wt_kernel<<<(D * D) / 256, 256, 0, stream>>>(W, wt, cbin);
    gcn_gemm_kernel<<<(n_nodes + 127) / 128, 256, 0, stream>>>(
        x, wt, support2, n_nodes);

    // 2) coarse-bin histogram + tiny scan
    gcn_chist_kernel<<<320, 256, 0, stream>>>(erow, cbin, n_edges);
    gcn_cscan_kernel<<<1, 512, 0, stream>>>(cbin, cbase, ccur, offsets,
                                            nbins, n_nodes, n_edges);

    // 3) two-stage binned CSR build
    gcn_binA_kernel<<<(n_edges + AW - 1) / AW, 256, 0, stream>>>(
        erow, ecol, eval, ccur, tmp8, n_edges, nbins);
    gcn_binB_kernel<<<nbins, 256, 0, stream>>>(tmp8, cbase, offsets, rec4, n_nodes);

    // 4) per-node reduce + fused tanh
    gcn_gather_kernel<<<(n_nodes + 3) / 4, 256, 0, stream>>>(
        (const unsigned int*)support2, rec4, offsets, out, n_nodes);
}

// Round 7
// 246.179 us; speedup vs baseline: 1.0788x; 1.0788x over previous
//
#include <hip/hip_runtime.h>
#include <hip/hip_bf16.h>
#include <hip/hip_fp16.h>
#include <math.h>

#define D 128
#define BIN_SHIFT 7      // 128 rows per coarse bin
#define BIN_ROWS 128
#define NB_MAX 1024      // >= nbins (782 for 100k nodes)
#define CPAD 16          // ints; one 64B line per coarse cursor
#define AW 4096          // edges per stage-A block window
#define LCAP 2560        // fused-gather LDS rec capacity (mean 2048, +11 sigma)

typedef _Float16 half8 __attribute__((ext_vector_type(8)));
typedef float floatx4 __attribute__((ext_vector_type(4)));
typedef float floatx2 __attribute__((ext_vector_type(2)));

// ---------------- W transpose + fp16 convert: wt[n][k] = f16(W[k][n]) ------
// Blocks 0-3 also zero the 1024 coarse-bin counters (no memset dispatch).
__global__ void gcn_wt_kernel(const float* __restrict__ W,
                              unsigned short* __restrict__ wt,
                              int* __restrict__ cbin) {
    const int i = blockIdx.x * 256 + threadIdx.x;  // i = n*128 + k
    const int n = i >> 7, k = i & 127;
    wt[i] = __half_as_ushort(__float2half_rn(W[k * D + n]));
    if (blockIdx.x < 4) cbin[blockIdx.x * 256 + threadIdx.x] = 0;  // NB_MAX
}

// ---------------- GEMM: support_f16 = fp16(x @ W), f16 MFMA ----------------
__global__ __launch_bounds__(256) void gcn_gemm_kernel(
        const float* __restrict__ x, const unsigned short* __restrict__ wt,
        unsigned short* __restrict__ support2, int n_nodes) {
    const int wave = threadIdx.x >> 6;
    const int lane = threadIdx.x & 63;
    const int q = lane >> 4;      // 0..3
    const int n16 = lane & 15;    // 0..15
    const int row_base = blockIdx.x * 128 + wave * 32;  // 32 rows per wave
    if (row_base >= n_nodes) return;   // 32 | 100000, no partial waves

    const half8* wt8 = (const half8*)wt;  // 16 B = 8 halves; wt row = 16 half8

    floatx4 acc[2][8];
#pragma unroll
    for (int mt = 0; mt < 2; ++mt)
#pragma unroll
        for (int nt = 0; nt < 8; ++nt) acc[mt][nt] = (floatx4){0.f, 0.f, 0.f, 0.f};

#pragma unroll
    for (int kc = 0; kc < 4; ++kc) {
        half8 b[8];
#pragma unroll
        for (int nt = 0; nt < 8; ++nt)
            b[nt] = wt8[(nt * 16 + n16) * 16 + kc * 4 + q];
#pragma unroll
        for (int mt = 0; mt < 2; ++mt) {
            const float* xp = x + (size_t)(row_base + mt * 16 + n16) * D
                                + kc * 32 + q * 8;
            const float4 f0 = *(const float4*)xp;
            const float4 f1 = *(const float4*)(xp + 4);
            half8 a;
            a[0] = (_Float16)f0.x; a[1] = (_Float16)f0.y;
            a[2] = (_Float16)f0.z; a[3] = (_Float16)f0.w;
            a[4] = (_Float16)f1.x; a[5] = (_Float16)f1.y;
            a[6] = (_Float16)f1.z; a[7] = (_Float16)f1.w;
#pragma unroll
            for (int nt = 0; nt < 8; ++nt)
                acc[mt][nt] = __builtin_amdgcn_mfma_f32_16x16x32_f16(
                    a, b[nt], acc[mt][nt], 0, 0, 0);
        }
    }

#pragma unroll
    for (int mt = 0; mt < 2; ++mt) {
        const int r0 = row_base + mt * 16 + q * 4;
#pragma unroll
        for (int nt = 0; nt < 8; ++nt) {
            const int col = nt * 16 + n16;
#pragma unroll
            for (int i = 0; i < 4; ++i)
                support2[(size_t)(r0 + i) * D + col] =
                    __half_as_ushort(__float2half_rn(acc[mt][nt][i]));
        }
    }
}

// ---------------- coarse-bin histogram (782 bins), LDS-aggregated ----------
__global__ __launch_bounds__(256) void gcn_chist_kernel(
        const int* __restrict__ erow, int* __restrict__ cbin, int n_edges) {
    __shared__ int h[NB_MAX];
    const int t = threadIdx.x;
#pragma unroll
    for (int s = 0; s < 4; ++s) h[t + s * 256] = 0;
    __syncthreads();
    const int stride = gridDim.x * 256 * 4;
    const int nv = n_edges & ~3;
    for (int i = (blockIdx.x * 256 + t) * 4; i + 3 < n_edges; i += stride) {
        const int4 r = *(const int4*)(erow + i);
        atomicAdd(&h[r.x >> BIN_SHIFT], 1);
        atomicAdd(&h[r.y >> BIN_SHIFT], 1);
        atomicAdd(&h[r.z >> BIN_SHIFT], 1);
        atomicAdd(&h[r.w >> BIN_SHIFT], 1);
    }
    if (blockIdx.x == 0) {  // scalar tail (none for 1.6M, kept for safety)
        for (int i = nv + t; i < n_edges; i += 256)
            atomicAdd(&h[erow[i] >> BIN_SHIFT], 1);
    }
    __syncthreads();
#pragma unroll
    for (int s = 0; s < 4; ++s) {
        const int b = t + s * 256;
        if (h[b] > 0) atomicAdd(&cbin[b], h[b]);
    }
}

// ---------------- scan of 782 coarse-bin totals (single block, 1024 thr) ---
__global__ __launch_bounds__(1024) void gcn_cscan_kernel(
        const int* __restrict__ cbin, int* __restrict__ cbase,
        int* __restrict__ ccur, int nbins, int n_edges) {
    __shared__ int sm[1024];
    const int t = threadIdx.x;
    const int v = (t < nbins) ? cbin[t] : 0;
    sm[t] = v;
    __syncthreads();
    for (int off = 1; off < 1024; off <<= 1) {
        int tv = (t >= off) ? sm[t - off] : 0;
        __syncthreads();
        sm[t] += tv;
        __syncthreads();
    }
    const int ex = sm[t] - v;
    if (t < nbins) { cbase[t] = ex; ccur[t * CPAD] = ex; }
    if (t == 0) cbase[nbins] = n_edges;
}

// ---------------- Stage A: block-local counting sort into coarse bins ------
// Round-5 staged structure (proven faster than direct scatter), adapted to
// 1024 bins (2 counters/thread in the block scan).
__global__ __launch_bounds__(512) void gcn_binA_kernel(
        const int* __restrict__ erow, const int* __restrict__ ecol,
        const float* __restrict__ eval, int* __restrict__ ccur,
        uint2* __restrict__ tmp8, int n_edges, int nbins) {
    __shared__ uint2 recs[AW];      // 32 KB
    __shared__ int hist[NB_MAX];
    __shared__ int lstart[NB_MAX];
    __shared__ int gbase[NB_MAX];
    __shared__ int sm[512];
    const int t = threadIdx.x;
    const int w0 = blockIdx.x * AW;
    const int wend = min(w0 + AW, n_edges);
    const int cnt = wend - w0;

    hist[t] = 0;
    hist[t + 512] = 0;
    __syncthreads();

    for (int i = w0 + t; i < wend; i += 512)
        atomicAdd(&hist[erow[i] >> BIN_SHIFT], 1);
    __syncthreads();

    // exclusive scan over 1024 counters (2 per thread)
    const int c0 = hist[2 * t], c1 = hist[2 * t + 1];
    const int s2 = c0 + c1;
    sm[t] = s2;
    __syncthreads();
    for (int off = 1; off < 512; off <<= 1) {
        int tv = (t >= off) ? sm[t - off] : 0;
        __syncthreads();
        sm[t] += tv;
        __syncthreads();
    }
    const int ex = sm[t] - s2;
    lstart[2 * t] = ex;
    lstart[2 * t + 1] = ex + c0;
    __syncthreads();

    // reserve contiguous global ranges (one atomic per used bin)
#pragma unroll
    for (int s = 0; s < 2; ++s) {
        const int b = 2 * t + s;
        const int c = hist[b];
        int gb = 0;
        if (b < nbins && c > 0) gb = atomicAdd(&ccur[b * CPAD], c);
        gbase[b] = gb;
    }
    __syncthreads();
    hist[2 * t] = lstart[2 * t];
    hist[2 * t + 1] = lstart[2 * t + 1];
    __syncthreads();

    // local placement into LDS
    for (int i = w0 + t; i < wend; i += 512) {
        const int r = erow[i];
        const int c = ecol[i];
        const unsigned short vh = __half_as_ushort(__float2half_rn(eval[i]));
        const int b = r >> BIN_SHIFT;
        const int p = atomicAdd(&hist[b], 1);
        recs[p] = make_uint2(((unsigned)r << 15) | vh, (unsigned)c);
    }
    __syncthreads();

    // ordered (coalesced-run) write-out
    for (int s = t; s < cnt; s += 512) {
        const uint2 rec = recs[s];
        const int b = (int)(rec.x >> 15) >> BIN_SHIFT;
        tmp8[gbase[b] + (s - lstart[b])] = rec;
    }
}

// ---------------- fused Stage B + gather + tanh ----------------------------
// One block per 128-row bin: per-row hist + 128-wide scan + placement into
// LDS recs (4 B each; whole bin ~8 KB), then 8 waves gather rows directly
// from LDS -> no rec4 write+read, no offsets round-trip, one fewer launch.
// Capacity fallback (never triggers for Poisson(2048) bins) places to the
// global rec4 scratch instead, same code path via generic pointer.
__global__ __launch_bounds__(512) void gcn_gatherB_kernel(
        const uint2* __restrict__ tmp8, const int* __restrict__ cbase,
        const unsigned int* __restrict__ support_u,
        unsigned int* __restrict__ rec4,
        float* __restrict__ out, int n_nodes) {
    __shared__ int rcnt[BIN_ROWS];     // counters -> cursors -> row ends
    __shared__ int rstart[BIN_ROWS];   // row starts (local)
    __shared__ int ssm[BIN_ROWS];
    __shared__ unsigned recs[LCAP];    // 10 KB
    const int bin = blockIdx.x;
    const int r0 = bin << BIN_SHIFT;
    const int t = threadIdx.x;
    if (t < BIN_ROWS) rcnt[t] = 0;
    __syncthreads();

    const int beg = cbase[bin];
    const int end = cbase[bin + 1];
    const int m = end - beg;

    // pass 1: per-row histogram (bin slice of tmp8 is contiguous)
    for (int i = beg + t; i < end; i += 512)
        atomicAdd(&rcnt[(int)(tmp8[i].x >> 15) - r0], 1);
    __syncthreads();

    // exclusive scan over 128 counters (threads 0..127)
    if (t < BIN_ROWS) ssm[t] = rcnt[t];
    __syncthreads();
    for (int off = 1; off < BIN_ROWS; off <<= 1) {
        int tv = (t >= off && t < BIN_ROWS) ? ssm[t - off] : 0;
        __syncthreads();
        if (t < BIN_ROWS) ssm[t] += tv;
        __syncthreads();
    }
    if (t < BIN_ROWS) {
        const int v = rcnt[t];
        rstart[t] = ssm[t] - v;
        rcnt[t] = ssm[t] - v;   // cursor
    }
    __syncthreads();

    const bool fast = (m <= LCAP);
    // pass 2: placement at local positions (LDS fast path / global fallback)
    if (fast) {
        for (int i = beg + t; i < end; i += 512) {
            const uint2 p = tmp8[i];
            const int pos = atomicAdd(&rcnt[(int)(p.x >> 15) - r0], 1);
            recs[pos] = (p.y << 15) | (p.x & 0x7FFFu);
        }
    } else {
        for (int i = beg + t; i < end; i += 512) {
            const uint2 p = tmp8[i];
            const int pos = atomicAdd(&rcnt[(int)(p.x >> 15) - r0], 1);
            rec4[beg + pos] = (p.y << 15) | (p.x & 0x7FFFu);
        }
    }
    __syncthreads();
    // post-placement: rcnt[lr] == local row end

    const unsigned* rp = fast ? (const unsigned*)recs : (rec4 + beg);
    const int wave = t >> 6;
    const int lane = t & 63;

    // gather: wave w handles rows w, w+8, ... (16 rows/wave)
    for (int lr = wave; lr < BIN_ROWS; lr += 8) {
        const int node = r0 + lr;
        if (node >= n_nodes) break;   // only trailing rows of last bin
        const int rs = rstart[lr];
        const int re = rcnt[lr];

        float ax = 0.f, ay = 0.f, bx = 0.f, by = 0.f;
        int e = rs;
        for (; e + 7 < re; e += 8) {
            unsigned r[8], s[8];
#pragma unroll
            for (int j = 0; j < 8; ++j) r[j] = rp[e + j];
#pragma unroll
            for (int j = 0; j < 8; ++j)
                s[j] = support_u[(size_t)(r[j] >> 15) * 64 + lane];
#pragma unroll
            for (int j = 0; j < 8; ++j) {
                const float v = __half2float(__ushort_as_half((unsigned short)(r[j] & 0x7FFFu)));
                const float slo = __half2float(__ushort_as_half((unsigned short)(s[j] & 0xFFFFu)));
                const float shi = __half2float(__ushort_as_half((unsigned short)(s[j] >> 16)));
                if (j & 1) { bx += v * slo; by += v * shi; }
                else       { ax += v * slo; ay += v * shi; }
            }
        }
        for (; e < re; ++e) {
            const unsigned r = rp[e];
            const unsigned s = support_u[(size_t)(r >> 15) * 64 + lane];
            const float v = __half2float(__ushort_as_half((unsigned short)(r & 0x7FFFu)));
            ax += v * __half2float(__ushort_as_half((unsigned short)(s & 0xFFFFu)));
            ay += v * __half2float(__ushort_as_half((unsigned short)(s >> 16)));
        }

        floatx2 res;
        res.x = tanhf(ax + bx);
        res.y = tanhf(ay + by);
        floatx2* out2 = (floatx2*)out;
        __builtin_nontemporal_store(res, &out2[(size_t)node * 64 + lane]);
    }
}

extern "C" void kernel_launch(void* const* d_in, const int* in_sizes, int n_in,
                              void* d_out, int out_size, void* d_ws, size_t ws_size,
                              hipStream_t stream) {
    const float* x    = (const float*)d_in[0];
    const float* W    = (const float*)d_in[1];
    const int*   erow = (const int*)d_in[2];
    const int*   ecol = (const int*)d_in[3];
    const float* eval = (const float*)d_in[4];
    float* out = (float*)d_out;

    const int n_nodes = in_sizes[0] / D;   // 100000
    const int n_edges = in_sizes[2];       // 1600000
    const int nbins = (n_nodes + BIN_ROWS - 1) >> BIN_SHIFT;      // 782

    // Workspace layout (16B alignment preserved per chunk)
    unsigned short* support2 = (unsigned short*)d_ws;             // 25.6 MB
    unsigned short* wt = support2 + (size_t)n_nodes * D;          // 32 KB
    uint2* tmp8   = (uint2*)(wt + D * D);                         // 12.8 MB
    unsigned int* rec4 = (unsigned int*)(tmp8 + n_edges);         // 6.4 MB (fallback scratch)
    int*  cbin    = (int*)(rec4 + n_edges);                       // NB_MAX
    int*  cbase   = cbin + NB_MAX;                                // nbins+1
    int*  ccur    = cbase + NB_MAX + 1;                           // nbins*CPAD

    // 1) wt = f16(W^T) (+ zero coarse-bin counters); support = fp16(x @ W)
    gcn_wt_kernel<<<(D * D) / 256, 256, 0, stream>>>(W, wt, cbin);
    gcn_gemm_kernel<<<(n_nodes + 127) / 128, 256, 0, stream>>>(
        x, wt, support2, n_nodes);

    // 2) coarse-bin histogram + tiny scan
    gcn_chist_kernel<<<320, 256, 0, stream>>>(erow, cbin, n_edges);
    gcn_cscan_kernel<<<1, 1024, 0, stream>>>(cbin, cbase, ccur, nbins, n_edges);

    // 3) stage-A binning, then fused stage-B + gather + tanh
    gcn_binA_kernel<<<(n_edges + AW - 1) / AW, 512, 0, stream>>>(
        erow, ecol, eval, ccur, tmp8, n_edges, nbins);
    gcn_gatherB_kernel<<<nbins, 512, 0, stream>>>(
        tmp8, cbase, (const unsigned int*)support2, rec4, out, n_nodes);
}